// Round 2
// baseline (422.692 us; speedup 1.0000x reference)
//
#include <hip/hip_runtime.h>

// N=1024, Cin=1024, Cy=256, H=W=128, inter=256 -- all fp32
#define HWDIM 128
#define NPIX  (HWDIM * HWDIM)   // 16384
#define CY    256
#define INTER 256
#define KTAPS 9
#define WEN   (CY * KTAPS)      // 2304
#define NW1   32                // k1 c-split (we partials)
#define NCS   8                 // A channel groups
#define CPG   32                // channels per A group
#define NPART2 256              // softmax partial pairs
#define NRG   4                 // q row-group split
#define NBLK  512               // fused grid

// ---------------------------------------------------------------------------
// Algebra: softmax over axis 1 cancels s_theta (constant along that axis) and
// the uniform phi-bias shift -> x, theta_*, phi_b dead. All 1024 output rows
// identical: z = gamma*(g_b + g_w . q).
//   we[cy,t] = sum_c wp[c]*phi_w[c,cy,t]
//   A[cg,t,pix] = sum_{cy in cg} we[cy,t]*y[cy,pix]     (tap-first: NO halo)
//   sphi[h,w] = sum_{cg,t} A[cg,t, shifted(h,w)]        (tiny L2 gather)
//   p = softmax(sphi);  q[cy,t] = sum_hw p[h-kh+1,w-kw+1]*y[cy,h,w]
//
// R1 post-mortem: cg::grid_group::sync() costs ~50us EACH on gfx950 (273us
// fused, VALUBusy 2.1%) -> replace with hand-rolled generation barrier
// (agent-scope atomics + s_sleep(1) spin + __threadfence for cross-XCD
// coherence). Barrier state in __device__ globals: generation is monotonic,
// needs no reset, immune to d_ws poisoning. P1 (we) folded into P2's LDS
// staging with BITWISE-IDENTICAL sum order -> 4 barriers instead of 5.
// NOTE (profiling): harness re-poison of the 256MB d_ws (fillBufferAligned,
// ~44us @ 6TB/s) + input restores are INSIDE dur_us -> ~58us fixed floor.
// ---------------------------------------------------------------------------

__device__ unsigned g_bar_cnt = 0;   // arrive counter (reset by last block)
__device__ unsigned g_bar_gen = 0;   // generation (monotonic, never reset)

__device__ __forceinline__ void gridbar() {
    __syncthreads();
    if (threadIdx.x == 0) {
        __threadfence();  // release: waitcnt + L2 writeback (cross-XCD vis)
        unsigned g = __hip_atomic_load(&g_bar_gen, __ATOMIC_RELAXED,
                                       __HIP_MEMORY_SCOPE_AGENT);
        unsigned a = __hip_atomic_fetch_add(&g_bar_cnt, 1u, __ATOMIC_RELAXED,
                                            __HIP_MEMORY_SCOPE_AGENT);
        if (a == NBLK - 1) {
            __hip_atomic_store(&g_bar_cnt, 0u, __ATOMIC_RELAXED,
                               __HIP_MEMORY_SCOPE_AGENT);
            __hip_atomic_store(&g_bar_gen, g + 1u, __ATOMIC_RELEASE,
                               __HIP_MEMORY_SCOPE_AGENT);
        } else {
            while (__hip_atomic_load(&g_bar_gen, __ATOMIC_RELAXED,
                                     __HIP_MEMORY_SCOPE_AGENT) == g)
                __builtin_amdgcn_s_sleep(1);   // 64-cycle backoff
        }
        __threadfence();  // acquire: invalidate stale L1/L2 lines
    }
    __syncthreads();
}

__device__ __forceinline__ float wave_red_sum(float v) {
    #pragma unroll
    for (int s = 32; s > 0; s >>= 1) v += __shfl_down(v, s, 64);
    return v;
}
__device__ __forceinline__ float wave_red_max(float v) {
    #pragma unroll
    for (int s = 32; s > 0; s >>= 1) v = fmaxf(v, __shfl_down(v, s, 64));
    return v;
}

// ===========================================================================
// Fused single-dispatch pipeline. grid=512x256, 2 blocks/CU co-resident
// (guaranteed by cooperative launch). 4 hand-rolled grid barriers.
// ===========================================================================
__global__ __launch_bounds__(256, 2)
void fused_all(const float* __restrict__ y,
               const float* __restrict__ phi_w,
               const float* __restrict__ concat_w,
               const float* __restrict__ g_w,
               const float* __restrict__ g_b,
               const float* __restrict__ gamma,
               float* __restrict__ out, int out_size,
               float* __restrict__ A,
               float* __restrict__ sphi,
               float* __restrict__ partials,
               float* __restrict__ q_part,
               float* __restrict__ row_part)
{
    __shared__ float smem[4500];          // 18 KB: p-tile (4420) + reductions
    const int b = blockIdx.x;
    const int t = threadIdx.x;
    const int wid = t >> 6, lane = t & 63;

    // ---- P2: A[cg][k][pix] = sum_{ch in cg} we[cg*CPG+ch,k]*y[ch,pix]
    // we computed in-block from L2-resident phi_w, bitwise-identical order
    // to the old k1(8-c fmaf chains) + 32-partial merge. 512 blk = 8cg x 64pg.
    {
        float* swe = smem;                // 288
        const int pg = b & 63, cgi = b >> 6;
        const int cgbase = cgi * CPG * KTAPS;    // 288*cgi

        for (int i = t; i < CPG * KTAPS; i += 256) {
            const float* pw = phi_w + cgbase + i;
            float s = 0.f;
            for (int p = 0; p < NW1; ++p) {      // 32 groups of 8 channels
                float partial = 0.f;
                #pragma unroll
                for (int j = 0; j < 8; ++j) {
                    int c = p * 8 + j;
                    partial = fmaf(concat_w[INTER + c], pw[c * WEN], partial);
                }
                s += partial;
            }
            swe[i] = s;
        }
        __syncthreads();

        int pix = pg * 256 + t;
        float acc[KTAPS];
        #pragma unroll
        for (int k = 0; k < KTAPS; ++k) acc[k] = 0.f;

        const float* yp = y + (size_t)cgi * CPG * NPIX + pix;
        #pragma unroll 8
        for (int ch = 0; ch < CPG; ++ch) {
            float yv = yp[ch * NPIX];
            const float* wk = swe + ch * KTAPS;   // wave-uniform LDS broadcast
            #pragma unroll
            for (int k = 0; k < KTAPS; ++k)
                acc[k] = fmaf(wk[k], yv, acc[k]);
        }
        #pragma unroll
        for (int k = 0; k < KTAPS; ++k)
            A[(size_t)(cgi * KTAPS + k) * NPIX + pix] = acc[k];
    }
    gridbar();

    // ---- P3: sphi[pix] = sum_{cg,k} A[cg][k][shifted]; softmax partials.
    // 256 active blocks; block covers 64 pixels x 4 term-groups.
    if (b < NPART2) {
        float* sred = smem;               // 256
        int tg = t >> 6, pl = t & 63;
        int pix = b * 64 + pl;
        int h = pix >> 7, w = pix & 127;

        int idx[KTAPS]; bool val[KTAPS];
        #pragma unroll
        for (int kh = 0; kh < 3; ++kh)
            #pragma unroll
            for (int kw = 0; kw < 3; ++kw) {
                int hh = h + kh - 1, ww = w + kw - 1;
                int k = kh * 3 + kw;
                val[k] = ((unsigned)hh < HWDIM) & ((unsigned)ww < HWDIM);
                idx[k] = hh * HWDIM + ww;
            }

        float acc = 0.f;
        #pragma unroll
        for (int cc = 0; cc < 2; ++cc) {
            const float* Ab = A + (size_t)(tg * 2 + cc) * KTAPS * NPIX;
            #pragma unroll
            for (int k = 0; k < KTAPS; ++k)
                if (val[k]) acc += Ab[(size_t)k * NPIX + idx[k]];
        }
        sred[t] = acc;
        __syncthreads();

        if (t < 64) {
            float v = sred[t] + sred[t + 64] + sred[t + 128] + sred[t + 192];
            sphi[b * 64 + t] = v;
            float m = wave_red_max(v);
            float M = __shfl(m, 0, 64);
            float e = expf(v - M);
            float s = wave_red_sum(e);
            if (t == 0) {
                partials[2 * b]     = M;
                partials[2 * b + 1] = s;
            }
        }
    }
    gridbar();

    // ---- P4: q_part[rg][cy*9+k] over a 32-row slice. 512 blocks =
    // 4 rg x 128 bc; each block handles cy0=2*bc, cy1=2*bc+1 sharing one
    // staged p tile.
    {
        float* sp  = smem;                        // 34*130 = 4420
        float* s4m = smem + 4420;                 // 4
        float* s4s = smem + 4424;                 // 4
        float (*sq4)[18] = (float (*)[18])(smem + 4428);  // 4x18
        const int rg = b >> 7;
        const int bc = b & 127;
        const int cy0 = bc * 2, cy1 = cy0 + 1;

        // merge 256 partial pairs -> M, invS (thread t owns pair t)
        float m = partials[2 * t], s = partials[2 * t + 1];
        float wm = wave_red_max(m);
        if (lane == 0) s4m[wid] = wm;
        __syncthreads();
        float M = fmaxf(fmaxf(s4m[0], s4m[1]), fmaxf(s4m[2], s4m[3]));
        float sv = s * expf(m - M);
        float wsum = wave_red_sum(sv);
        if (lane == 0) s4s[wid] = wsum;
        __syncthreads();
        float invS = 1.f / (s4s[0] + s4s[1] + s4s[2] + s4s[3]);

        // stage p tile: sp[r][col] = p[rg*32 + r - 1][col - 1], zero-padded
        for (int i = t; i < 34 * 130; i += 256) {
            int r = i / 130, col = i - r * 130;
            int gr = rg * 32 + r - 1, gc = col - 1;
            float v = 0.f;
            if ((unsigned)gr < HWDIM && (unsigned)gc < HWDIM)
                v = expf(sphi[gr * HWDIM + gc] - M) * invS;
            sp[i] = v;
        }
        __syncthreads();

        const float* yc0 = y + (size_t)cy0 * NPIX;
        const float* yc1 = y + (size_t)cy1 * NPIX;
        float acc0[KTAPS], acc1[KTAPS];
        #pragma unroll
        for (int k = 0; k < KTAPS; ++k) { acc0[k] = 0.f; acc1[k] = 0.f; }
        int c = t & 127, vg = t >> 7;

        for (int j = 0; j < 4; ++j) {
            int lr0 = vg * 4 + j * 8;             // local row base (0..28)
            float pv[6][3];
            #pragma unroll
            for (int u = 0; u < 6; ++u)
                #pragma unroll
                for (int v = 0; v < 3; ++v)
                    pv[u][v] = sp[(lr0 + u) * 130 + c + v];
            #pragma unroll
            for (int dr = 0; dr < 4; ++dr) {
                float y0 = yc0[(rg * 32 + lr0 + dr) * HWDIM + c];
                float y1 = yc1[(rg * 32 + lr0 + dr) * HWDIM + c];
                #pragma unroll
                for (int kh = 0; kh < 3; ++kh)
                    #pragma unroll
                    for (int kw = 0; kw < 3; ++kw) {
                        float p = pv[dr + 2 - kh][2 - kw];
                        acc0[kh * 3 + kw] = fmaf(p, y0, acc0[kh * 3 + kw]);
                        acc1[kh * 3 + kw] = fmaf(p, y1, acc1[kh * 3 + kw]);
                    }
            }
        }

        #pragma unroll
        for (int k = 0; k < KTAPS; ++k) {
            float v0 = wave_red_sum(acc0[k]);
            float v1 = wave_red_sum(acc1[k]);
            if (lane == 0) { sq4[wid][k] = v0; sq4[wid][9 + k] = v1; }
        }
        __syncthreads();
        if (t < KTAPS) {
            q_part[rg * WEN + cy0 * KTAPS + t] =
                sq4[0][t] + sq4[1][t] + sq4[2][t] + sq4[3][t];
            q_part[rg * WEN + cy1 * KTAPS + t] =
                sq4[0][9 + t] + sq4[1][9 + t] + sq4[2][9 + t] + sq4[3][9 + t];
        }
    }
    gridbar();

    // ---- P5: row_part[half][c] = g_w[c, half-slice] . q  (merge 4 partials)
    // all 512 blocks = 2 half x 256 c
    {
        float* s4 = smem;                 // 4
        int c = b & 255, half = b >> 8;
        int base = half * (WEN / 2);      // 1152

        const float* gw = g_w + (size_t)c * WEN;
        float acc = 0.f;
        #pragma unroll
        for (int j = 0; j < 5; ++j) {
            int o = base + j * 256 + t;
            if (o < base + WEN / 2) {
                float qv = q_part[o] + q_part[WEN + o] +
                           q_part[2 * WEN + o] + q_part[3 * WEN + o];
                acc = fmaf(gw[o], qv, acc);
            }
        }
        float v = wave_red_sum(acc);
        if (lane == 0) s4[wid] = v;
        __syncthreads();
        if (t == 0)
            row_part[half * 256 + c] = s4[0] + s4[1] + s4[2] + s4[3];
    }
    gridbar();

    // ---- P6: out[i*256+c] = gamma*(g_b[c] + row0[c] + row1[c]); col c == t
    {
        float val = gamma[0] * (g_b[t] + row_part[t] + row_part[256 + t]);
        int gid0 = b * 256 + t;
        if (gid0 < out_size) out[gid0] = val;
        int gid1 = (b + 512) * 256 + t;
        if (gid1 < out_size) out[gid1] = val;
    }
}

// ===========================================================================
// Fallback: the proven 6-kernel pipeline (unchanged), used only if the
// cooperative launch is rejected at runtime.
// ===========================================================================
__global__ void k1_wepart(const float* __restrict__ phi_w,
                          const float* __restrict__ concat_w,
                          float* __restrict__ we_part) {
    int b = blockIdx.x, t = threadIdx.x;
    int cg = b / 9, og = b - cg * 9;
    int o = og * 256 + t;
    const float* pw = phi_w + o;
    float acc = 0.f;
    #pragma unroll
    for (int j = 0; j < 8; ++j) {
        int c = cg * 8 + j;
        acc = fmaf(concat_w[INTER + c], pw[c * WEN], acc);
    }
    we_part[cg * WEN + o] = acc;
}

__global__ void k2a_taps(const float* __restrict__ y,
                         const float* __restrict__ we_part,
                         float* __restrict__ A) {
    __shared__ float swe[CPG * KTAPS];
    int t = threadIdx.x;
    int pg = blockIdx.x & 63;
    int cg = blockIdx.x >> 6;

    for (int i = t; i < CPG * KTAPS; i += 256) {
        float s = 0.f;
        #pragma unroll
        for (int p = 0; p < NW1; ++p)
            s += we_part[p * WEN + cg * CPG * KTAPS + i];
        swe[i] = s;
    }
    __syncthreads();

    int pix = pg * 256 + t;
    float acc[KTAPS];
    #pragma unroll
    for (int k = 0; k < KTAPS; ++k) acc[k] = 0.f;

    const float* yp = y + (size_t)cg * CPG * NPIX + pix;
    #pragma unroll 4
    for (int ch = 0; ch < CPG; ++ch) {
        float yv = yp[ch * NPIX];
        const float* wk = swe + ch * KTAPS;
        #pragma unroll
        for (int k = 0; k < KTAPS; ++k)
            acc[k] = fmaf(wk[k], yv, acc[k]);
    }
    #pragma unroll
    for (int k = 0; k < KTAPS; ++k)
        A[(size_t)(cg * KTAPS + k) * NPIX + pix] = acc[k];
}

__global__ void k2b_sphi(const float* __restrict__ A,
                         float* __restrict__ sphi,
                         float* __restrict__ partials) {
    __shared__ float sred[256];
    int t = threadIdx.x;
    int tg = t >> 6, pl = t & 63;
    int pix = blockIdx.x * 64 + pl;
    int h = pix >> 7, w = pix & 127;

    int idx[KTAPS]; bool val[KTAPS];
    #pragma unroll
    for (int kh = 0; kh < 3; ++kh)
        #pragma unroll
        for (int kw = 0; kw < 3; ++kw) {
            int hh = h + kh - 1, ww = w + kw - 1;
            int k = kh * 3 + kw;
            val[k] = ((unsigned)hh < HWDIM) & ((unsigned)ww < HWDIM);
            idx[k] = hh * HWDIM + ww;
        }

    float acc = 0.f;
    #pragma unroll
    for (int cc = 0; cc < 2; ++cc) {
        const float* Ab = A + (size_t)(tg * 2 + cc) * KTAPS * NPIX;
        #pragma unroll
        for (int k = 0; k < KTAPS; ++k)
            if (val[k]) acc += Ab[(size_t)k * NPIX + idx[k]];
    }
    sred[t] = acc;
    __syncthreads();

    if (t < 64) {
        float v = sred[t] + sred[t + 64] + sred[t + 128] + sred[t + 192];
        sphi[blockIdx.x * 64 + t] = v;
        float m = wave_red_max(v);
        float M = __shfl(m, 0, 64);
        float e = expf(v - M);
        float s = wave_red_sum(e);
        if (t == 0) {
            partials[2 * blockIdx.x]     = M;
            partials[2 * blockIdx.x + 1] = s;
        }
    }
}

__global__ void k4_q(const float* __restrict__ y,
                     const float* __restrict__ sphi,
                     const float* __restrict__ partials,
                     float* __restrict__ q_part) {
    __shared__ float sp[34 * 130];
    __shared__ float s4m[4], s4s[4];
    __shared__ float sq4[4][KTAPS];
    int cy = blockIdx.x & 255;
    int rg = blockIdx.x >> 8;
    int t = threadIdx.x;
    int wid = t >> 6, lane = t & 63;

    float m = partials[2 * t], s = partials[2 * t + 1];
    float wm = wave_red_max(m);
    if (lane == 0) s4m[wid] = wm;
    __syncthreads();
    float M = fmaxf(fmaxf(s4m[0], s4m[1]), fmaxf(s4m[2], s4m[3]));
    float sv = s * expf(m - M);
    float wsum = wave_red_sum(sv);
    if (lane == 0) s4s[wid] = wsum;
    __syncthreads();
    float invS = 1.f / (s4s[0] + s4s[1] + s4s[2] + s4s[3]);

    for (int i = t; i < 34 * 130; i += 256) {
        int r = i / 130, col = i - r * 130;
        int gr = rg * 32 + r - 1, gc = col - 1;
        float v = 0.f;
        if ((unsigned)gr < HWDIM && (unsigned)gc < HWDIM)
            v = expf(sphi[gr * HWDIM + gc] - M) * invS;
        sp[i] = v;
    }
    __syncthreads();

    const float* yc = y + (size_t)cy * NPIX;
    float acc[KTAPS];
    #pragma unroll
    for (int k = 0; k < KTAPS; ++k) acc[k] = 0.f;
    int c = t & 127, vg = t >> 7;

    for (int j = 0; j < 4; ++j) {
        int lr0 = vg * 4 + j * 8;
        float pv[6][3];
        #pragma unroll
        for (int u = 0; u < 6; ++u)
            #pragma unroll
            for (int v = 0; v < 3; ++v)
                pv[u][v] = sp[(lr0 + u) * 130 + c + v];
        #pragma unroll
        for (int dr = 0; dr < 4; ++dr) {
            float yv = yc[(rg * 32 + lr0 + dr) * HWDIM + c];
            #pragma unroll
            for (int kh = 0; kh < 3; ++kh)
                #pragma unroll
                for (int kw = 0; kw < 3; ++kw)
                    acc[kh * 3 + kw] = fmaf(pv[dr + 2 - kh][2 - kw], yv,
                                            acc[kh * 3 + kw]);
        }
    }

    #pragma unroll
    for (int k = 0; k < KTAPS; ++k) {
        float v = wave_red_sum(acc[k]);
        if (lane == 0) sq4[wid][k] = v;
    }
    __syncthreads();
    if (t < KTAPS)
        q_part[rg * WEN + cy * KTAPS + t] =
            sq4[0][t] + sq4[1][t] + sq4[2][t] + sq4[3][t];
}

__global__ void k5_row(const float* __restrict__ g_w,
                       const float* __restrict__ q_part,
                       float* __restrict__ row_part) {
    __shared__ float s4[4];
    int t = threadIdx.x;
    int c = blockIdx.x & 255, half = blockIdx.x >> 8;
    int base = half * (WEN / 2);

    const float* gw = g_w + (size_t)c * WEN;
    float acc = 0.f;
    #pragma unroll
    for (int j = 0; j < 5; ++j) {
        int o = base + j * 256 + t;
        if (o < base + WEN / 2) {
            float qv = q_part[o] + q_part[WEN + o] +
                       q_part[2 * WEN + o] + q_part[3 * WEN + o];
            acc = fmaf(gw[o], qv, acc);
        }
    }
    float v = wave_red_sum(acc);
    int wid = t >> 6, lane = t & 63;
    if (lane == 0) s4[wid] = v;
    __syncthreads();
    if (t == 0)
        row_part[half * 256 + c] = s4[0] + s4[1] + s4[2] + s4[3];
}

__global__ void k6_bcast(const float* __restrict__ row_part,
                         const float* __restrict__ g_b,
                         const float* __restrict__ gamma,
                         float* __restrict__ out, int out_size) {
    __shared__ float sr[256];
    int t = threadIdx.x;
    sr[t] = gamma[0] * (g_b[t] + row_part[t] + row_part[256 + t]);
    __syncthreads();
    int gid = blockIdx.x * 256 + t;
    if (gid < out_size) out[gid] = sr[t];
}

extern "C" void kernel_launch(void* const* d_in, const int* in_sizes, int n_in,
                              void* d_out, int out_size, void* d_ws, size_t ws_size,
                              hipStream_t stream) {
    // inputs: x, y, g_w, g_b, phi_w, phi_b, theta_w, theta_b, concat_w, gamma
    const float* y        = (const float*)d_in[1];
    const float* g_w      = (const float*)d_in[2];
    const float* g_b      = (const float*)d_in[3];
    const float* phi_w    = (const float*)d_in[4];
    const float* concat_w = (const float*)d_in[8];
    const float* gamma    = (const float*)d_in[9];
    float* out = (float*)d_out;

    float* ws       = (float*)d_ws;
    float* we_part  = ws;                            // 32*2304   = 73728 (fallback only)
    float* A        = we_part + NW1 * WEN;           // 8*9*16384 = 1179648
    float* sphi     = A + (size_t)NCS * KTAPS * NPIX;// 16384
    float* partials = sphi + NPIX;                   // 512
    float* q_part   = partials + 2 * NPART2;         // 4*2304
    float* row_part = q_part + NRG * WEN;            // 512
    (void)in_sizes; (void)n_in; (void)ws_size;

    int osz = out_size;
    void* args[] = {
        (void*)&y, (void*)&phi_w, (void*)&concat_w, (void*)&g_w,
        (void*)&g_b, (void*)&gamma, (void*)&out, (void*)&osz,
        (void*)&A, (void*)&sphi, (void*)&partials,
        (void*)&q_part, (void*)&row_part
    };
    hipError_t err = hipLaunchCooperativeKernel(
        reinterpret_cast<void*>(fused_all), dim3(NBLK), dim3(256),
        args, 0, stream);

    if (err != hipSuccess) {
        // fallback: proven 6-kernel pipeline
        hipLaunchKernelGGL(k1_wepart, dim3(288),      dim3(256), 0, stream,
                           phi_w, concat_w, we_part);
        hipLaunchKernelGGL(k2a_taps,  dim3(64 * NCS), dim3(256), 0, stream,
                           y, we_part, A);
        hipLaunchKernelGGL(k2b_sphi,  dim3(NPART2),   dim3(256), 0, stream,
                           A, sphi, partials);
        hipLaunchKernelGGL(k4_q,      dim3(NRG * CY), dim3(256), 0, stream,
                           y, sphi, partials, q_part);
        hipLaunchKernelGGL(k5_row,    dim3(512),      dim3(256), 0, stream,
                           g_w, q_part, row_part);
        hipLaunchKernelGGL(k6_bcast,  dim3((out_size + 255) / 256), dim3(256),
                           0, stream, row_part, g_b, gamma, out, out_size);
    }
}

// Round 3
// 233.875 us; speedup vs baseline: 1.8073x; 1.8073x over previous
//
#include <hip/hip_runtime.h>

// N=1024, Cin=1024, Cy=256, H=W=128, inter=256 -- all fp32
#define HWDIM 128
#define NPIX  (HWDIM * HWDIM)   // 16384
#define CY    256
#define INTER 256
#define KTAPS 9
#define WEN   (CY * KTAPS)      // 2304
#define NW1   32                // we c-split (8-chain partial groups)
#define NCS   8                 // A channel groups
#define CPG   32                // channels per A group
#define NPART2 256              // softmax partial pairs
#define NRG   4                 // q row-group split

// ---------------------------------------------------------------------------
// Algebra: softmax over axis 1 cancels s_theta (constant along that axis) and
// the uniform phi-bias shift -> x, theta_*, phi_b dead. All 1024 output rows
// identical: z = gamma*(g_b + g_w . q).
//   we[cy,t] = sum_c wp[c]*phi_w[c,cy,t]
//   A[cg,t,pix] = sum_{cy in cg} we[cy,t]*y[cy,pix]     (tap-first: NO halo)
//   sphi[h,w] = sum_{cg,t} A[cg,t, shifted(h,w)]        (tiny L2 gather)
//   p = softmax(sphi);  q[cy,t] = sum_hw p[h-kh+1,w-kw+1]*y[cy,h,w]
//
// R1/R2 post-mortem: in-kernel grid sync on MI355X costs 50-100us PER BARRIER
// (cg::sync 273us/5bar; hand-rolled atomic+fence 411us/4bar, VALUBusy ~2.5%).
// The cross-XCD release/acquire (buffer_wbl2+inv per block, serialized per
// XCD L2) is the cost -- a command-processor kernel boundary (~6-7us) is 10x
// cheaper. So: NO fusion. Instead cut 6 dispatches -> 4 with bitwise-exact
// merges: kA=k1(we in-LDS)+k2a (verified absmax 0.0 in R2-P2), kC=k4 with
// cy-pair blocks (verified R1/R2), kD=k5+k6 (k5's exact reduce tree, then
// the block broadcasts its column to all 1024 rows).
// NOTE (profiling): harness re-poison of the 256MB d_ws (fillBufferAligned,
// ~44us @ 6TB/s) + input restores are INSIDE dur_us -> ~58us fixed floor.
// ---------------------------------------------------------------------------

__device__ __forceinline__ float wave_red_sum(float v) {
    #pragma unroll
    for (int s = 32; s > 0; s >>= 1) v += __shfl_down(v, s, 64);
    return v;
}
__device__ __forceinline__ float wave_red_max(float v) {
    #pragma unroll
    for (int s = 32; s > 0; s >>= 1) v = fmaxf(v, __shfl_down(v, s, 64));
    return v;
}

// kA: (k1+k2a) A[cg][k][pix] = sum_{ch in cg} we[cg*CPG+ch,k]*y[ch,pix]
// we computed in-block from L2-resident phi_w, bitwise-identical order to
// old k1 (8-c fmaf chains) + 32-partial sequential merge. 512 blk = 8cg x 64pg.
__global__ void kA_taps(const float* __restrict__ y,
                        const float* __restrict__ phi_w,
                        const float* __restrict__ concat_w,
                        float* __restrict__ A) {
    __shared__ float swe[CPG * KTAPS];      // 288
    int t = threadIdx.x;
    int pg = blockIdx.x & 63;
    int cg = blockIdx.x >> 6;
    const int cgbase = cg * CPG * KTAPS;    // 288*cg

    for (int i = t; i < CPG * KTAPS; i += 256) {
        const float* pw = phi_w + cgbase + i;
        float s = 0.f;
        for (int p = 0; p < NW1; ++p) {     // 32 groups of 8 channels
            float partial = 0.f;
            #pragma unroll
            for (int j = 0; j < 8; ++j) {
                int c = p * 8 + j;
                partial = fmaf(concat_w[INTER + c], pw[c * WEN], partial);
            }
            s += partial;
        }
        swe[i] = s;
    }
    __syncthreads();

    int pix = pg * 256 + t;
    float acc[KTAPS];
    #pragma unroll
    for (int k = 0; k < KTAPS; ++k) acc[k] = 0.f;

    const float* yp = y + (size_t)cg * CPG * NPIX + pix;
    #pragma unroll 8
    for (int ch = 0; ch < CPG; ++ch) {
        float yv = yp[ch * NPIX];
        const float* wk = swe + ch * KTAPS;   // wave-uniform LDS broadcast
        #pragma unroll
        for (int k = 0; k < KTAPS; ++k)
            acc[k] = fmaf(wk[k], yv, acc[k]);
    }
    #pragma unroll
    for (int k = 0; k < KTAPS; ++k)
        A[(size_t)(cg * KTAPS + k) * NPIX + pix] = acc[k];
}

// kB: sphi[pix] = sum_{cg,k} A[cg][k][shifted]; per-block softmax partials.
// grid 256; block covers 64 pixels x 4 term-groups (2 cg x 9 taps each).
__global__ void kB_sphi(const float* __restrict__ A,
                        float* __restrict__ sphi,
                        float* __restrict__ partials) {
    __shared__ float sred[256];
    int t = threadIdx.x;
    int tg = t >> 6, pl = t & 63;
    int pix = blockIdx.x * 64 + pl;
    int h = pix >> 7, w = pix & 127;

    int idx[KTAPS]; bool val[KTAPS];
    #pragma unroll
    for (int kh = 0; kh < 3; ++kh)
        #pragma unroll
        for (int kw = 0; kw < 3; ++kw) {
            int hh = h + kh - 1, ww = w + kw - 1;
            int k = kh * 3 + kw;
            val[k] = ((unsigned)hh < HWDIM) & ((unsigned)ww < HWDIM);
            idx[k] = hh * HWDIM + ww;
        }

    float acc = 0.f;
    #pragma unroll
    for (int cc = 0; cc < 2; ++cc) {
        const float* Ab = A + (size_t)(tg * 2 + cc) * KTAPS * NPIX;
        #pragma unroll
        for (int k = 0; k < KTAPS; ++k)
            if (val[k]) acc += Ab[(size_t)k * NPIX + idx[k]];
    }
    sred[t] = acc;
    __syncthreads();

    if (t < 64) {
        float v = sred[t] + sred[t + 64] + sred[t + 128] + sred[t + 192];
        sphi[blockIdx.x * 64 + t] = v;
        float m = wave_red_max(v);
        float M = __shfl(m, 0, 64);
        float e = expf(v - M);
        float s = wave_red_sum(e);
        if (t == 0) {
            partials[2 * blockIdx.x]     = M;
            partials[2 * blockIdx.x + 1] = s;
        }
    }
}

// kC: q_part[rg][cy*9+k] over a 32-row slice. 512 blocks = 4 rg x 128 bc;
// each block handles cy0=2*bc, cy1=2*bc+1 sharing one staged p tile.
__global__ void kC_q(const float* __restrict__ y,
                     const float* __restrict__ sphi,
                     const float* __restrict__ partials,
                     float* __restrict__ q_part) {
    __shared__ float sp[34 * 130];        // padded p tile, 17.7 KB
    __shared__ float s4m[4], s4s[4];
    __shared__ float sq4[4][2 * KTAPS];
    const int rg = blockIdx.x >> 7;
    const int bc = blockIdx.x & 127;
    const int cy0 = bc * 2, cy1 = cy0 + 1;
    int t = threadIdx.x;
    int wid = t >> 6, lane = t & 63;

    // merge 256 partial pairs -> M, invS (thread t owns pair t)
    float m = partials[2 * t], s = partials[2 * t + 1];
    float wm = wave_red_max(m);
    if (lane == 0) s4m[wid] = wm;
    __syncthreads();
    float M = fmaxf(fmaxf(s4m[0], s4m[1]), fmaxf(s4m[2], s4m[3]));
    float sv = s * expf(m - M);
    float wsum = wave_red_sum(sv);
    if (lane == 0) s4s[wid] = wsum;
    __syncthreads();
    float invS = 1.f / (s4s[0] + s4s[1] + s4s[2] + s4s[3]);

    // stage p tile: sp[r][col] = p[rg*32 + r - 1][col - 1], zero-padded
    for (int i = t; i < 34 * 130; i += 256) {
        int r = i / 130, col = i - r * 130;
        int gr = rg * 32 + r - 1, gc = col - 1;
        float v = 0.f;
        if ((unsigned)gr < HWDIM && (unsigned)gc < HWDIM)
            v = expf(sphi[gr * HWDIM + gc] - M) * invS;
        sp[i] = v;
    }
    __syncthreads();

    const float* yc0 = y + (size_t)cy0 * NPIX;
    const float* yc1 = y + (size_t)cy1 * NPIX;
    float acc0[KTAPS], acc1[KTAPS];
    #pragma unroll
    for (int k = 0; k < KTAPS; ++k) { acc0[k] = 0.f; acc1[k] = 0.f; }
    int c = t & 127, vg = t >> 7;

    for (int j = 0; j < 4; ++j) {
        int lr0 = vg * 4 + j * 8;         // local row base (0..28)
        float pv[6][3];
        #pragma unroll
        for (int u = 0; u < 6; ++u)
            #pragma unroll
            for (int v = 0; v < 3; ++v)
                pv[u][v] = sp[(lr0 + u) * 130 + c + v];
        #pragma unroll
        for (int dr = 0; dr < 4; ++dr) {
            float y0 = yc0[(rg * 32 + lr0 + dr) * HWDIM + c];
            float y1 = yc1[(rg * 32 + lr0 + dr) * HWDIM + c];
            #pragma unroll
            for (int kh = 0; kh < 3; ++kh)
                #pragma unroll
                for (int kw = 0; kw < 3; ++kw) {
                    float p = pv[dr + 2 - kh][2 - kw];
                    acc0[kh * 3 + kw] = fmaf(p, y0, acc0[kh * 3 + kw]);
                    acc1[kh * 3 + kw] = fmaf(p, y1, acc1[kh * 3 + kw]);
                }
        }
    }

    #pragma unroll
    for (int k = 0; k < KTAPS; ++k) {
        float v0 = wave_red_sum(acc0[k]);
        float v1 = wave_red_sum(acc1[k]);
        if (lane == 0) { sq4[wid][k] = v0; sq4[wid][KTAPS + k] = v1; }
    }
    __syncthreads();
    if (t < KTAPS) {
        q_part[rg * WEN + cy0 * KTAPS + t] =
            sq4[0][t] + sq4[1][t] + sq4[2][t] + sq4[3][t];
        q_part[rg * WEN + cy1 * KTAPS + t] =
            sq4[0][KTAPS + t] + sq4[1][KTAPS + t] +
            sq4[2][KTAPS + t] + sq4[3][KTAPS + t];
    }
}

// kD: (k5+k6) one block per column c. Both halves of g_w[c,:].q with k5's
// exact per-half chain + shuffle tree + s4[0..3] order, then broadcast
// val = gamma*(g_b[c]+r0+r1) to out[i*256+c] for all 1024 rows.
__global__ void kD_zout(const float* __restrict__ g_w,
                        const float* __restrict__ q_part,
                        const float* __restrict__ g_b,
                        const float* __restrict__ gamma,
                        float* __restrict__ out, int out_size) {
    __shared__ float s4a[4], s4b[4];
    int t = threadIdx.x;
    int c = blockIdx.x;
    int wid = t >> 6, lane = t & 63;

    const float* gw = g_w + (size_t)c * WEN;

    // half 0 (base 0) -- identical chain to k5
    float acc0 = 0.f;
    #pragma unroll
    for (int j = 0; j < 5; ++j) {
        int o = j * 256 + t;
        if (o < WEN / 2) {
            float qv = q_part[o] + q_part[WEN + o] +
                       q_part[2 * WEN + o] + q_part[3 * WEN + o];
            acc0 = fmaf(gw[o], qv, acc0);
        }
    }
    // half 1 (base 1152)
    float acc1 = 0.f;
    #pragma unroll
    for (int j = 0; j < 5; ++j) {
        int o = (WEN / 2) + j * 256 + t;
        if (o < WEN) {
            float qv = q_part[o] + q_part[WEN + o] +
                       q_part[2 * WEN + o] + q_part[3 * WEN + o];
            acc1 = fmaf(gw[o], qv, acc1);
        }
    }
    float v0 = wave_red_sum(acc0);
    float v1 = wave_red_sum(acc1);
    if (lane == 0) { s4a[wid] = v0; s4b[wid] = v1; }
    __syncthreads();
    float r0 = s4a[0] + s4a[1] + s4a[2] + s4a[3];
    float r1 = s4b[0] + s4b[1] + s4b[2] + s4b[3];
    float val = gamma[0] * (g_b[c] + r0 + r1);

    // broadcast column c to all rows (scattered 4B stores, L2-combined)
    for (int i = t; i < 1024; i += 256) {
        int gid = i * 256 + c;
        if (gid < out_size) out[gid] = val;
    }
}

extern "C" void kernel_launch(void* const* d_in, const int* in_sizes, int n_in,
                              void* d_out, int out_size, void* d_ws, size_t ws_size,
                              hipStream_t stream) {
    // inputs: x, y, g_w, g_b, phi_w, phi_b, theta_w, theta_b, concat_w, gamma
    const float* y        = (const float*)d_in[1];
    const float* g_w      = (const float*)d_in[2];
    const float* g_b      = (const float*)d_in[3];
    const float* phi_w    = (const float*)d_in[4];
    const float* concat_w = (const float*)d_in[8];
    const float* gamma    = (const float*)d_in[9];
    float* out = (float*)d_out;

    float* ws       = (float*)d_ws;
    float* A        = ws;                             // 8*9*16384 = 1179648
    float* sphi     = A + (size_t)NCS * KTAPS * NPIX; // 16384
    float* partials = sphi + NPIX;                    // 512
    float* q_part   = partials + 2 * NPART2;          // 4*2304
    (void)in_sizes; (void)n_in; (void)ws_size;

    hipLaunchKernelGGL(kA_taps, dim3(64 * NCS), dim3(256), 0, stream,
                       y, phi_w, concat_w, A);
    hipLaunchKernelGGL(kB_sphi, dim3(NPART2),   dim3(256), 0, stream,
                       A, sphi, partials);
    hipLaunchKernelGGL(kC_q,    dim3(NRG * 128), dim3(256), 0, stream,
                       y, sphi, partials, q_part);
    hipLaunchKernelGGL(kD_zout, dim3(CY),       dim3(256), 0, stream,
                       g_w, q_part, g_b, gamma, out, out_size);
}

// Round 4
// 122.613 us; speedup vs baseline: 3.4474x; 1.9074x over previous
//
#include <hip/hip_runtime.h>

// N=1024, Cin=1024, Cy=256, H=W=128, inter=256 -- all fp32
#define HWDIM 128
#define NPIX  (HWDIM * HWDIM)   // 16384
#define CY    256
#define INTER 256
#define KTAPS 9
#define WEN   (CY * KTAPS)      // 2304
#define NW1   32                // k1 c-split (we partials)
#define NCS   8                 // A channel groups
#define CPG   32                // channels per A group
#define NPART2 256              // softmax partial pairs
#define NRG   4                 // q row-group split

// ---------------------------------------------------------------------------
// Algebra: softmax over axis 1 cancels s_theta (constant along that axis) and
// the uniform phi-bias shift -> x, theta_*, phi_b dead. All 1024 output rows
// identical: z = gamma*(g_b + g_w . q).
//   we[cy,t] = sum_c wp[c]*phi_w[c,cy,t]
//   A[cg,t,pix] = sum_{cy in cg} we[cy,t]*y[cy,pix]     (tap-first: NO halo)
//   sphi[h,w] = sum_{cg,t} A[cg,t, shifted(h,w)]        (tiny L2 gather)
//   p = softmax(sphi);  q[cy,t] = sum_hw p[h-kh+1,w-kw+1]*y[cy,h,w]
//
// Session ledger:
//  R1/R2: in-kernel grid sync costs 50-100us/barrier on MI355X (cross-XCD L2
//    wb/inv per block). Kernel boundary (~5-7us) is 10x cheaper. NO fusion.
//  R3: folding k1 into k2a (per-block redundant we recompute) = latency
//    disaster: 512 blocks x serial 32-group chain over strided phi_w, 2
//    blocks/CU -> kA 150-200us, VALUBusy 3%. Keep k1 SEPARATE (288 blocks,
//    8 coalesced loads/thread). Dispatch merges must not create redundant
//    latency-bound recompute.
//  R3 data: small-kernel dispatch ~5-7us each; kC (cy-pair k4) and kD (k5+k6)
//    verified bitwise (absmax 0.0).
//  This round: best verified pieces, 5 dispatches: k1, k2a, kB, kC, kD.
// NOTE (profiling): harness re-poison of the 256MB d_ws (fillBufferAligned,
// ~44us @ 6TB/s) + input restores are INSIDE dur_us -> ~58us fixed floor.
// ---------------------------------------------------------------------------

__device__ __forceinline__ float wave_red_sum(float v) {
    #pragma unroll
    for (int s = 32; s > 0; s >>= 1) v += __shfl_down(v, s, 64);
    return v;
}
__device__ __forceinline__ float wave_red_max(float v) {
    #pragma unroll
    for (int s = 32; s > 0; s >>= 1) v = fmaxf(v, __shfl_down(v, s, 64));
    return v;
}

// K1: we_part[cg][o] = sum_{c in 8-slice} wp[c]*phi_w[c,o]
// grid 288 = 32 cg x 9 og; threads span o (coalesced phi_w rows)
__global__ void k1_wepart(const float* __restrict__ phi_w,
                          const float* __restrict__ concat_w,
                          float* __restrict__ we_part) {
    int b = blockIdx.x, t = threadIdx.x;
    int cg = b / 9, og = b - cg * 9;
    int o = og * 256 + t;
    const float* pw = phi_w + o;
    float acc = 0.f;
    #pragma unroll
    for (int j = 0; j < 8; ++j) {
        int c = cg * 8 + j;
        acc = fmaf(concat_w[INTER + c], pw[c * WEN], acc);
    }
    we_part[cg * WEN + o] = acc;
}

// K2a: A[cg][k][pix] = sum_{ch in cg} we[cg*CPG+ch, k] * y[ch,pix]
// grid 512 = 8 cg x 64 pg; streams y coalesced once.
__global__ void k2a_taps(const float* __restrict__ y,
                         const float* __restrict__ we_part,
                         float* __restrict__ A) {
    __shared__ float swe[CPG * KTAPS];      // 288
    int t = threadIdx.x;
    int pg = blockIdx.x & 63;
    int cg = blockIdx.x >> 6;

    for (int i = t; i < CPG * KTAPS; i += 256) {
        float s = 0.f;
        #pragma unroll
        for (int p = 0; p < NW1; ++p)
            s += we_part[p * WEN + cg * CPG * KTAPS + i];
        swe[i] = s;
    }
    __syncthreads();

    int pix = pg * 256 + t;
    float acc[KTAPS];
    #pragma unroll
    for (int k = 0; k < KTAPS; ++k) acc[k] = 0.f;

    const float* yp = y + (size_t)cg * CPG * NPIX + pix;
    #pragma unroll 4
    for (int ch = 0; ch < CPG; ++ch) {
        float yv = yp[ch * NPIX];
        const float* wk = swe + ch * KTAPS;   // wave-uniform LDS broadcast
        #pragma unroll
        for (int k = 0; k < KTAPS; ++k)
            acc[k] = fmaf(wk[k], yv, acc[k]);
    }
    #pragma unroll
    for (int k = 0; k < KTAPS; ++k)
        A[(size_t)(cg * KTAPS + k) * NPIX + pix] = acc[k];
}

// kB: sphi[pix] = sum_{cg,k} A[cg][k][shifted]; per-block softmax partials.
// grid 256; block covers 64 pixels x 4 term-groups (2 cg x 9 taps each).
__global__ void kB_sphi(const float* __restrict__ A,
                        float* __restrict__ sphi,
                        float* __restrict__ partials) {
    __shared__ float sred[256];
    int t = threadIdx.x;
    int tg = t >> 6, pl = t & 63;
    int pix = blockIdx.x * 64 + pl;
    int h = pix >> 7, w = pix & 127;

    int idx[KTAPS]; bool val[KTAPS];
    #pragma unroll
    for (int kh = 0; kh < 3; ++kh)
        #pragma unroll
        for (int kw = 0; kw < 3; ++kw) {
            int hh = h + kh - 1, ww = w + kw - 1;
            int k = kh * 3 + kw;
            val[k] = ((unsigned)hh < HWDIM) & ((unsigned)ww < HWDIM);
            idx[k] = hh * HWDIM + ww;
        }

    float acc = 0.f;
    #pragma unroll
    for (int cc = 0; cc < 2; ++cc) {
        const float* Ab = A + (size_t)(tg * 2 + cc) * KTAPS * NPIX;
        #pragma unroll
        for (int k = 0; k < KTAPS; ++k)
            if (val[k]) acc += Ab[(size_t)k * NPIX + idx[k]];
    }
    sred[t] = acc;
    __syncthreads();

    if (t < 64) {
        float v = sred[t] + sred[t + 64] + sred[t + 128] + sred[t + 192];
        sphi[blockIdx.x * 64 + t] = v;
        float m = wave_red_max(v);
        float M = __shfl(m, 0, 64);
        float e = expf(v - M);
        float s = wave_red_sum(e);
        if (t == 0) {
            partials[2 * blockIdx.x]     = M;
            partials[2 * blockIdx.x + 1] = s;
        }
    }
}

// kC: q_part[rg][cy*9+k] over a 32-row slice. 512 blocks = 4 rg x 128 bc;
// each block handles cy0=2*bc, cy1=2*bc+1 sharing one staged p tile.
__global__ void kC_q(const float* __restrict__ y,
                     const float* __restrict__ sphi,
                     const float* __restrict__ partials,
                     float* __restrict__ q_part) {
    __shared__ float sp[34 * 130];        // padded p tile, 17.7 KB
    __shared__ float s4m[4], s4s[4];
    __shared__ float sq4[4][2 * KTAPS];
    const int rg = blockIdx.x >> 7;
    const int bc = blockIdx.x & 127;
    const int cy0 = bc * 2, cy1 = cy0 + 1;
    int t = threadIdx.x;
    int wid = t >> 6, lane = t & 63;

    // merge 256 partial pairs -> M, invS (thread t owns pair t)
    float m = partials[2 * t], s = partials[2 * t + 1];
    float wm = wave_red_max(m);
    if (lane == 0) s4m[wid] = wm;
    __syncthreads();
    float M = fmaxf(fmaxf(s4m[0], s4m[1]), fmaxf(s4m[2], s4m[3]));
    float sv = s * expf(m - M);
    float wsum = wave_red_sum(sv);
    if (lane == 0) s4s[wid] = wsum;
    __syncthreads();
    float invS = 1.f / (s4s[0] + s4s[1] + s4s[2] + s4s[3]);

    // stage p tile: sp[r][col] = p[rg*32 + r - 1][col - 1], zero-padded
    for (int i = t; i < 34 * 130; i += 256) {
        int r = i / 130, col = i - r * 130;
        int gr = rg * 32 + r - 1, gc = col - 1;
        float v = 0.f;
        if ((unsigned)gr < HWDIM && (unsigned)gc < HWDIM)
            v = expf(sphi[gr * HWDIM + gc] - M) * invS;
        sp[i] = v;
    }
    __syncthreads();

    const float* yc0 = y + (size_t)cy0 * NPIX;
    const float* yc1 = y + (size_t)cy1 * NPIX;
    float acc0[KTAPS], acc1[KTAPS];
    #pragma unroll
    for (int k = 0; k < KTAPS; ++k) { acc0[k] = 0.f; acc1[k] = 0.f; }
    int c = t & 127, vg = t >> 7;

    for (int j = 0; j < 4; ++j) {
        int lr0 = vg * 4 + j * 8;         // local row base (0..28)
        float pv[6][3];
        #pragma unroll
        for (int u = 0; u < 6; ++u)
            #pragma unroll
            for (int v = 0; v < 3; ++v)
                pv[u][v] = sp[(lr0 + u) * 130 + c + v];
        #pragma unroll
        for (int dr = 0; dr < 4; ++dr) {
            float y0 = yc0[(rg * 32 + lr0 + dr) * HWDIM + c];
            float y1 = yc1[(rg * 32 + lr0 + dr) * HWDIM + c];
            #pragma unroll
            for (int kh = 0; kh < 3; ++kh)
                #pragma unroll
                for (int kw = 0; kw < 3; ++kw) {
                    float p = pv[dr + 2 - kh][2 - kw];
                    acc0[kh * 3 + kw] = fmaf(p, y0, acc0[kh * 3 + kw]);
                    acc1[kh * 3 + kw] = fmaf(p, y1, acc1[kh * 3 + kw]);
                }
        }
    }

    #pragma unroll
    for (int k = 0; k < KTAPS; ++k) {
        float v0 = wave_red_sum(acc0[k]);
        float v1 = wave_red_sum(acc1[k]);
        if (lane == 0) { sq4[wid][k] = v0; sq4[wid][KTAPS + k] = v1; }
    }
    __syncthreads();
    if (t < KTAPS) {
        q_part[rg * WEN + cy0 * KTAPS + t] =
            sq4[0][t] + sq4[1][t] + sq4[2][t] + sq4[3][t];
        q_part[rg * WEN + cy1 * KTAPS + t] =
            sq4[0][KTAPS + t] + sq4[1][KTAPS + t] +
            sq4[2][KTAPS + t] + sq4[3][KTAPS + t];
    }
}

// kD: (k5+k6) one block per column c. Both halves of g_w[c,:].q with k5's
// exact per-half chain + shuffle tree + s4[0..3] order, then broadcast
// val = gamma*(g_b[c]+r0+r1) to out[i*256+c] for all 1024 rows.
__global__ void kD_zout(const float* __restrict__ g_w,
                        const float* __restrict__ q_part,
                        const float* __restrict__ g_b,
                        const float* __restrict__ gamma,
                        float* __restrict__ out, int out_size) {
    __shared__ float s4a[4], s4b[4];
    int t = threadIdx.x;
    int c = blockIdx.x;
    int wid = t >> 6, lane = t & 63;

    const float* gw = g_w + (size_t)c * WEN;

    // half 0 (base 0) -- identical chain to k5
    float acc0 = 0.f;
    #pragma unroll
    for (int j = 0; j < 5; ++j) {
        int o = j * 256 + t;
        if (o < WEN / 2) {
            float qv = q_part[o] + q_part[WEN + o] +
                       q_part[2 * WEN + o] + q_part[3 * WEN + o];
            acc0 = fmaf(gw[o], qv, acc0);
        }
    }
    // half 1 (base 1152)
    float acc1 = 0.f;
    #pragma unroll
    for (int j = 0; j < 5; ++j) {
        int o = (WEN / 2) + j * 256 + t;
        if (o < WEN) {
            float qv = q_part[o] + q_part[WEN + o] +
                       q_part[2 * WEN + o] + q_part[3 * WEN + o];
            acc1 = fmaf(gw[o], qv, acc1);
        }
    }
    float v0 = wave_red_sum(acc0);
    float v1 = wave_red_sum(acc1);
    if (lane == 0) { s4a[wid] = v0; s4b[wid] = v1; }
    __syncthreads();
    float r0 = s4a[0] + s4a[1] + s4a[2] + s4a[3];
    float r1 = s4b[0] + s4b[1] + s4b[2] + s4b[3];
    float val = gamma[0] * (g_b[c] + r0 + r1);

    // broadcast column c to all rows (scattered 4B stores, L2-combined)
    for (int i = t; i < 1024; i += 256) {
        int gid = i * 256 + c;
        if (gid < out_size) out[gid] = val;
    }
}

extern "C" void kernel_launch(void* const* d_in, const int* in_sizes, int n_in,
                              void* d_out, int out_size, void* d_ws, size_t ws_size,
                              hipStream_t stream) {
    // inputs: x, y, g_w, g_b, phi_w, phi_b, theta_w, theta_b, concat_w, gamma
    const float* y        = (const float*)d_in[1];
    const float* g_w      = (const float*)d_in[2];
    const float* g_b      = (const float*)d_in[3];
    const float* phi_w    = (const float*)d_in[4];
    const float* concat_w = (const float*)d_in[8];
    const float* gamma    = (const float*)d_in[9];
    float* out = (float*)d_out;

    float* ws       = (float*)d_ws;
    float* we_part  = ws;                             // 32*2304   = 73728
    float* A        = we_part + NW1 * WEN;            // 8*9*16384 = 1179648
    float* sphi     = A + (size_t)NCS * KTAPS * NPIX; // 16384
    float* partials = sphi + NPIX;                    // 512
    float* q_part   = partials + 2 * NPART2;          // 4*2304
    (void)in_sizes; (void)n_in; (void)ws_size;

    hipLaunchKernelGGL(k1_wepart, dim3(288),       dim3(256), 0, stream,
                       phi_w, concat_w, we_part);
    hipLaunchKernelGGL(k2a_taps,  dim3(64 * NCS),  dim3(256), 0, stream,
                       y, we_part, A);
    hipLaunchKernelGGL(kB_sphi,   dim3(NPART2),    dim3(256), 0, stream,
                       A, sphi, partials);
    hipLaunchKernelGGL(kC_q,      dim3(NRG * 128), dim3(256), 0, stream,
                       y, sphi, partials, q_part);
    hipLaunchKernelGGL(kD_zout,   dim3(CY),        dim3(256), 0, stream,
                       g_w, q_part, g_b, gamma, out, out_size);
}

// Round 5
// 117.672 us; speedup vs baseline: 3.5921x; 1.0420x over previous
//
#include <hip/hip_runtime.h>

// N=1024, Cin=1024, Cy=256, H=W=128, inter=256 -- all fp32
#define HWDIM 128
#define NPIX  (HWDIM * HWDIM)   // 16384
#define CY    256
#define INTER 256
#define KTAPS 9
#define WEN   (CY * KTAPS)      // 2304
#define NW1   32                // k1 c-split (we partials)
#define NCS   8                 // A channel groups
#define CPG   32                // channels per A group
#define NPART2 256              // softmax partial pairs (k2b grid)
#define NRG   4                 // k4 row-group split

// ---------------------------------------------------------------------------
// Algebra: softmax over axis 1 cancels s_theta (constant along that axis) and
// the uniform phi-bias shift -> x, theta_*, phi_b dead. All 1024 output rows
// identical: z = gamma*(g_b + g_w . q).
//   we[cy,t] = sum_c wp[c]*phi_w[c,cy,t]
//   A[cg,t,pix] = sum_{cy in cg} we[cy,t]*y[cy,pix]     (tap-first: NO halo)
//   sphi[h,w] = sum_{cg,t} A[cg,t, shifted(h,w)]        (tiny L2 gather)
//   p = softmax(sphi);  q[cy,t] = sum_hw p[h-kh+1,w-kw+1]*y[cy,h,w]
//
// Session ledger (MI355X structural findings):
//  R1/R2: in-kernel grid-wide sync costs 50-100us PER BARRIER on this chip
//    (cg::sync 273us/5bar; hand atomic+fence 411us/4bar; VALUBusy ~2.5%).
//    Cross-XCD L2 wb/inv per arriving block is the cost. Kernel boundaries
//    (~<=7us) are 10x cheaper. NO grid-sync fusion.
//  R3: folding k1's we into k2a (512 blocks x serial 32-group chain over
//    strided phi_w) = latency disaster (kA 150-200us, VALUBusy 3%). Merges
//    must not create redundant latency-bound recompute.
//  R4: 5-dispatch recompose (kC cy-pair, kD=k5+k6 with per-column scatter
//    stores) = 122.6us ~= R0's 119.3 (noise). kD's 262144 uncoalesced 4B
//    stores ate the dispatch saving. Dispatch gaps are smaller than modeled;
//    launches pipeline.
//  Conclusion: this 6-kernel pipeline is the empirical optimum. dur_us is
//    dominated by the harness floor: 256MB d_ws re-poison (fillBufferAligned
//    ~44us @ ~75% achievable HBM) + input restores, INSIDE dur_us. Compute
//    bodies sum to ~15-20us, each near its own BW/latency floor.
// ---------------------------------------------------------------------------

__device__ __forceinline__ float wave_red_sum(float v) {
    #pragma unroll
    for (int s = 32; s > 0; s >>= 1) v += __shfl_down(v, s, 64);
    return v;
}
__device__ __forceinline__ float wave_red_max(float v) {
    #pragma unroll
    for (int s = 32; s > 0; s >>= 1) v = fmaxf(v, __shfl_down(v, s, 64));
    return v;
}

// K1: we_part[cg][o] = sum_{c in 8-slice} wp[c]*phi_w[c,o]
// grid 288 = 32 cg x 9 og; threads span o (coalesced phi_w rows)
__global__ void k1_wepart(const float* __restrict__ phi_w,
                          const float* __restrict__ concat_w,
                          float* __restrict__ we_part) {
    int b = blockIdx.x, t = threadIdx.x;
    int cg = b / 9, og = b - cg * 9;
    int o = og * 256 + t;
    const float* pw = phi_w + o;
    float acc = 0.f;
    #pragma unroll
    for (int j = 0; j < 8; ++j) {
        int c = cg * 8 + j;
        acc = fmaf(concat_w[INTER + c], pw[c * WEN], acc);
    }
    we_part[cg * WEN + o] = acc;
}

// K2a: A[cg][k][pix] = sum_{ch in cg} we[cg*CPG+ch, k] * y[ch,pix]
// grid 512 = 8 cg x 64 pg; streams y coalesced once.
__global__ void k2a_taps(const float* __restrict__ y,
                         const float* __restrict__ we_part,
                         float* __restrict__ A) {
    __shared__ float swe[CPG * KTAPS];      // 288
    int t = threadIdx.x;
    int pg = blockIdx.x & 63;
    int cg = blockIdx.x >> 6;

    for (int i = t; i < CPG * KTAPS; i += 256) {
        float s = 0.f;
        #pragma unroll
        for (int p = 0; p < NW1; ++p)
            s += we_part[p * WEN + cg * CPG * KTAPS + i];
        swe[i] = s;
    }
    __syncthreads();

    int pix = pg * 256 + t;
    float acc[KTAPS];
    #pragma unroll
    for (int k = 0; k < KTAPS; ++k) acc[k] = 0.f;

    const float* yp = y + (size_t)cg * CPG * NPIX + pix;
    #pragma unroll 4
    for (int ch = 0; ch < CPG; ++ch) {
        float yv = yp[ch * NPIX];
        const float* wk = swe + ch * KTAPS;   // wave-uniform LDS broadcast
        #pragma unroll
        for (int k = 0; k < KTAPS; ++k)
            acc[k] = fmaf(wk[k], yv, acc[k]);
    }
    #pragma unroll
    for (int k = 0; k < KTAPS; ++k)
        A[(size_t)(cg * KTAPS + k) * NPIX + pix] = acc[k];
}

// K2b: sphi[pix] = sum_{cg,k} A[cg][k][shifted]; per-block softmax partials.
// grid 256; block covers 64 pixels x 4 term-groups (2 cg x 9 taps each).
__global__ void k2b_sphi(const float* __restrict__ A,
                         float* __restrict__ sphi,
                         float* __restrict__ partials) {
    __shared__ float sred[256];
    int t = threadIdx.x;
    int tg = t >> 6, pl = t & 63;
    int pix = blockIdx.x * 64 + pl;
    int h = pix >> 7, w = pix & 127;

    int idx[KTAPS]; bool val[KTAPS];
    #pragma unroll
    for (int kh = 0; kh < 3; ++kh)
        #pragma unroll
        for (int kw = 0; kw < 3; ++kw) {
            int hh = h + kh - 1, ww = w + kw - 1;
            int k = kh * 3 + kw;
            val[k] = ((unsigned)hh < HWDIM) & ((unsigned)ww < HWDIM);
            idx[k] = hh * HWDIM + ww;
        }

    float acc = 0.f;
    #pragma unroll
    for (int cc = 0; cc < 2; ++cc) {
        const float* Ab = A + (size_t)(tg * 2 + cc) * KTAPS * NPIX;
        #pragma unroll
        for (int k = 0; k < KTAPS; ++k)
            if (val[k]) acc += Ab[(size_t)k * NPIX + idx[k]];
    }
    sred[t] = acc;
    __syncthreads();

    if (t < 64) {
        float v = sred[t] + sred[t + 64] + sred[t + 128] + sred[t + 192];
        sphi[blockIdx.x * 64 + t] = v;
        float m = wave_red_max(v);
        float M = __shfl(m, 0, 64);
        float e = expf(v - M);
        float s = wave_red_sum(e);
        if (t == 0) {
            partials[2 * blockIdx.x]     = M;
            partials[2 * blockIdx.x + 1] = s;
        }
    }
}

// K4: q_part[rg][cy*9+t] over a 32-row slice; merges the 256 softmax
// partials in-block. grid 1024 = 4 rg x 256 cy.
__global__ void k4_q(const float* __restrict__ y,
                     const float* __restrict__ sphi,
                     const float* __restrict__ partials,
                     float* __restrict__ q_part) {
    __shared__ float sp[34 * 130];        // padded p tile, 17.7 KB
    __shared__ float s4m[4], s4s[4];
    __shared__ float sq4[4][KTAPS];
    int cy = blockIdx.x & 255;
    int rg = blockIdx.x >> 8;
    int t = threadIdx.x;
    int wid = t >> 6, lane = t & 63;

    // merge 256 partial pairs -> M, invS (thread t owns pair t)
    float m = partials[2 * t], s = partials[2 * t + 1];
    float wm = wave_red_max(m);
    if (lane == 0) s4m[wid] = wm;
    __syncthreads();
    float M = fmaxf(fmaxf(s4m[0], s4m[1]), fmaxf(s4m[2], s4m[3]));
    float sv = s * expf(m - M);
    float wsum = wave_red_sum(sv);
    if (lane == 0) s4s[wid] = wsum;
    __syncthreads();
    float invS = 1.f / (s4s[0] + s4s[1] + s4s[2] + s4s[3]);

    // stage p tile: sp[r][col] = p[rg*32 + r - 1][col - 1], zero-padded
    for (int i = t; i < 34 * 130; i += 256) {
        int r = i / 130, col = i - r * 130;
        int gr = rg * 32 + r - 1, gc = col - 1;
        float v = 0.f;
        if ((unsigned)gr < HWDIM && (unsigned)gc < HWDIM)
            v = expf(sphi[gr * HWDIM + gc] - M) * invS;
        sp[i] = v;
    }
    __syncthreads();

    const float* yc = y + (size_t)cy * NPIX;
    float acc[KTAPS];
    #pragma unroll
    for (int k = 0; k < KTAPS; ++k) acc[k] = 0.f;
    int c = t & 127, vg = t >> 7;

    for (int j = 0; j < 4; ++j) {
        int lr0 = vg * 4 + j * 8;         // local row base (0..28)
        float pv[6][3];
        #pragma unroll
        for (int u = 0; u < 6; ++u)
            #pragma unroll
            for (int v = 0; v < 3; ++v)
                pv[u][v] = sp[(lr0 + u) * 130 + c + v];
        #pragma unroll
        for (int dr = 0; dr < 4; ++dr) {
            float yv = yc[(rg * 32 + lr0 + dr) * HWDIM + c];
            #pragma unroll
            for (int kh = 0; kh < 3; ++kh)
                #pragma unroll
                for (int kw = 0; kw < 3; ++kw)
                    acc[kh * 3 + kw] = fmaf(pv[dr + 2 - kh][2 - kw], yv,
                                            acc[kh * 3 + kw]);
        }
    }

    #pragma unroll
    for (int k = 0; k < KTAPS; ++k) {
        float v = wave_red_sum(acc[k]);
        if (lane == 0) sq4[wid][k] = v;
    }
    __syncthreads();
    if (t < KTAPS)
        q_part[rg * WEN + cy * KTAPS + t] =
            sq4[0][t] + sq4[1][t] + sq4[2][t] + sq4[3][t];
}

// K5: row_part[half][c] = g_w[c, half-slice] . q  (q merged from 4 partials)
// grid 512 = 2 half x 256 c
__global__ void k5_row(const float* __restrict__ g_w,
                       const float* __restrict__ q_part,
                       float* __restrict__ row_part) {
    __shared__ float s4[4];
    int t = threadIdx.x;
    int c = blockIdx.x & 255, half = blockIdx.x >> 8;
    int base = half * (WEN / 2);          // 1152

    const float* gw = g_w + (size_t)c * WEN;
    float acc = 0.f;
    #pragma unroll
    for (int j = 0; j < 5; ++j) {
        int o = base + j * 256 + t;
        if (o < base + WEN / 2) {
            float qv = q_part[o] + q_part[WEN + o] +
                       q_part[2 * WEN + o] + q_part[3 * WEN + o];
            acc = fmaf(gw[o], qv, acc);
        }
    }
    float v = wave_red_sum(acc);
    int wid = t >> 6, lane = t & 63;
    if (lane == 0) s4[wid] = v;
    __syncthreads();
    if (t == 0)
        row_part[half * 256 + c] = s4[0] + s4[1] + s4[2] + s4[3];
}

// K6: out[i*256+c] = gamma*(g_b[c] + row_part[0][c] + row_part[1][c])
__global__ void k6_bcast(const float* __restrict__ row_part,
                         const float* __restrict__ g_b,
                         const float* __restrict__ gamma,
                         float* __restrict__ out, int out_size) {
    __shared__ float sr[256];
    int t = threadIdx.x;
    sr[t] = gamma[0] * (g_b[t] + row_part[t] + row_part[256 + t]);
    __syncthreads();
    int gid = blockIdx.x * 256 + t;
    if (gid < out_size) out[gid] = sr[t];
}

extern "C" void kernel_launch(void* const* d_in, const int* in_sizes, int n_in,
                              void* d_out, int out_size, void* d_ws, size_t ws_size,
                              hipStream_t stream) {
    // inputs: x, y, g_w, g_b, phi_w, phi_b, theta_w, theta_b, concat_w, gamma
    const float* y        = (const float*)d_in[1];
    const float* g_w      = (const float*)d_in[2];
    const float* g_b      = (const float*)d_in[3];
    const float* phi_w    = (const float*)d_in[4];
    const float* concat_w = (const float*)d_in[8];
    const float* gamma    = (const float*)d_in[9];
    float* out = (float*)d_out;

    float* ws       = (float*)d_ws;
    float* we_part  = ws;                            // 32*2304   = 73728
    float* A        = we_part + NW1 * WEN;           // 8*9*16384 = 1179648
    float* sphi     = A + (size_t)NCS * KTAPS * NPIX;// 16384
    float* partials = sphi + NPIX;                   // 512
    float* q_part   = partials + 2 * NPART2;         // 4*2304
    float* row_part = q_part + NRG * WEN;            // 512
    (void)in_sizes; (void)n_in; (void)ws_size;

    hipLaunchKernelGGL(k1_wepart, dim3(288),      dim3(256), 0, stream,
                       phi_w, concat_w, we_part);
    hipLaunchKernelGGL(k2a_taps,  dim3(64 * NCS), dim3(256), 0, stream,
                       y, we_part, A);
    hipLaunchKernelGGL(k2b_sphi,  dim3(NPART2),   dim3(256), 0, stream,
                       A, sphi, partials);
    hipLaunchKernelGGL(k4_q,      dim3(NRG * CY), dim3(256), 0, stream,
                       y, sphi, partials, q_part);
    hipLaunchKernelGGL(k5_row,    dim3(512),      dim3(256), 0, stream,
                       g_w, q_part, row_part);
    hipLaunchKernelGGL(k6_bcast,  dim3((out_size + 255) / 256), dim3(256), 0,
                       stream, row_part, g_b, gamma, out, out_size);
}